// Round 3
// baseline (8254.177 us; speedup 1.0000x reference)
//
#include <hip/hip_runtime.h>
#include <hip/hip_bf16.h>

typedef __attribute__((ext_vector_type(8))) short bf16x8;
typedef __attribute__((ext_vector_type(4))) float f32x4;

#define HID 1024
#define BATCH 32
#define NACT (BATCH * HID)        // 32768
#define NWIH (3 * 3 * HID * HID)  // 9,437,184 (plane stride, all layers)
#define LSTRIDE (3 * HID * HID)   // per-layer offset inside one plane
#define NFC (2500 * HID)          // 2,560,000

__device__ __forceinline__ f32x4 mfma16(bf16x8 a, bf16x8 b, f32x4 c) {
  return __builtin_amdgcn_mfma_f32_16x16x32_bf16(a, b, c, 0, 0, 0);
}

__device__ __forceinline__ __hip_bfloat16 bf_from_bits(unsigned short u) {
  union { unsigned short s; __hip_bfloat16 b; } cv; cv.s = u; return cv.b;
}

// Exact 3-plane (or approx 2/1-plane) split of fp32 into bf16 planes.
// hi/mid by truncation, last plane RTN (exact for NP==3: 8+8+8 = 24 mantissa bits).
template <int NP>
__device__ __forceinline__ void split_store(float v, __hip_bfloat16* base, int stride, int idx) {
  float r = v;
#pragma unroll
  for (int p = 0; p < NP; ++p) {
    __hip_bfloat16 pb;
    if (p == NP - 1) pb = __float2bfloat16(r);
    else pb = bf_from_bits((unsigned short)(__float_as_uint(r) >> 16));
    base[p * stride + idx] = pb;
    r -= __bfloat162float(pb);
  }
}

// ---------------- weight split fp32 -> NP bf16 planes (once per launch) ----------------
template <int NP>
__global__ void convert_weights(const float* __restrict__ Wih, const float* __restrict__ Whh,
                                const float* __restrict__ fcw,
                                __hip_bfloat16* __restrict__ WIHP, __hip_bfloat16* __restrict__ WHHP,
                                __hip_bfloat16* __restrict__ FCWP) {
  int i0 = blockIdx.x * blockDim.x + threadIdx.x;
  int st = gridDim.x * blockDim.x;
  for (int i = i0; i < NWIH; i += st) {
    split_store<NP>(Wih[i], WIHP, NWIH, i);
    split_store<NP>(Whh[i], WHHP, NWIH, i);
  }
  for (int i = i0; i < NFC; i += st) split_store<NP>(fcw[i], FCWP, NFC, i);
}

// ---------------- setup: zero h set0 (fp32 + planes), split x -> XBP, trig tables ----------------
template <int NP>
__global__ void setup_kernel(const float* __restrict__ x_in, float* __restrict__ h0,
                             __hip_bfloat16* __restrict__ hbp0, __hip_bfloat16* __restrict__ xbp,
                             float* __restrict__ cosM, float* __restrict__ sinM) {
  int i0 = blockIdx.x * blockDim.x + threadIdx.x;
  int st = gridDim.x * blockDim.x;
  for (int k = i0; k < 3 * NACT; k += st) h0[k] = 0.0f;
  for (int k = i0; k < 3 * NP * NACT; k += st) hbp0[k] = bf_from_bits(0);
  for (int k = i0; k < NACT; k += st) split_store<NP>(x_in[k], xbp, NACT, k);
  for (int k = i0; k < 32 * 50; k += st) {
    int a = k / 50, n = k % 50;
    int ka = (a + 34) % 50;  // fftshift+crop: kept row a is frequency (a+34)%50
    int ph = (ka * n) % 50;  // exact integer angle reduction
    float ang = 6.283185307179586f * (float)ph / 50.0f;
    cosM[k] = cosf(ang);
    sinM[k] = sinf(ang);
  }
}

// ---------------- fused GRU layer: split-bf16 MFMA gi+gh + pointwise ----------------
// grid 64 blocks (j-tiles of 16 over 1024 features; 3 gates handled internally),
// block 256 = 4 waves, wave w owns K range [w*256, w*256+256)
template <int NP>
__global__ __launch_bounds__(256) void gru_layer(
    const __hip_bfloat16* __restrict__ Wih,  // layer base in plane 0; plane stride NWIH
    const __hip_bfloat16* __restrict__ Whh,
    const float* __restrict__ bih, const float* __restrict__ bhh,
    const __hip_bfloat16* __restrict__ Ain,   // layer input planes, stride NACT
    const float* __restrict__ h_in,           // old h fp32
    const __hip_bfloat16* __restrict__ hb_in, // old h planes, stride NACT
    float* __restrict__ h_out, __hip_bfloat16* __restrict__ hb_out) {
  __shared__ float red[3 * 64 * 48];
  int tid = threadIdx.x;
  int L = tid & 63, w = tid >> 6;
  int jt = blockIdx.x * 16;
  int col = L & 15, quad = L >> 4;
  int kb = w * 256, aoff = quad * 8;

  f32x4 zero = {0.f, 0.f, 0.f, 0.f};
  f32x4 accI[3][2], accH[3][2];
#pragma unroll
  for (int g = 0; g < 3; ++g)
#pragma unroll
    for (int mh = 0; mh < 2; ++mh) { accI[g][mh] = zero; accH[g][mh] = zero; }

  for (int it = 0; it < 8; ++it) {
    int k0 = kb + it * 32 + aoff;
    bf16x8 xa[NP][2], ha[NP][2], bi[NP][3], bh[NP][3];
#pragma unroll
    for (int mh = 0; mh < 2; ++mh) {
      int r = (mh * 16 + col) * HID + k0;
#pragma unroll
      for (int p = 0; p < NP; ++p) {
        xa[p][mh] = *(const bf16x8*)(Ain + p * NACT + r);
        ha[p][mh] = *(const bf16x8*)(hb_in + p * NACT + r);
      }
    }
#pragma unroll
    for (int g = 0; g < 3; ++g) {
      int rr = (g * HID + jt + col) * HID + k0;  // B^T layout: row = output feature j
#pragma unroll
      for (int p = 0; p < NP; ++p) {
        bi[p][g] = *(const bf16x8*)(Wih + p * NWIH + rr);
        bh[p][g] = *(const bf16x8*)(Whh + p * NWIH + rr);
      }
    }
#pragma unroll
    for (int g = 0; g < 3; ++g)
#pragma unroll
      for (int mh = 0; mh < 2; ++mh)
#pragma unroll
        for (int p = 0; p < NP; ++p)
#pragma unroll
          for (int q = 0; q < NP - p; ++q) {  // keep plane pairs with p+q <= NP-1
            accI[g][mh] = mfma16(xa[p][mh], bi[q][g], accI[g][mh]);
            accH[g][mh] = mfma16(ha[p][mh], bh[q][g], accH[g][mh]);
          }
  }

  if (w > 0) {
    float* p = &red[((w - 1) * 64 + L) * 48];
#pragma unroll
    for (int g = 0; g < 3; ++g)
#pragma unroll
      for (int mh = 0; mh < 2; ++mh) {
        *(f32x4*)(p + (g * 2 + mh) * 4) = accI[g][mh];
        *(f32x4*)(p + 24 + (g * 2 + mh) * 4) = accH[g][mh];
      }
  }
  __syncthreads();
  if (w == 0) {
#pragma unroll
    for (int s = 0; s < 3; ++s) {
      const float* p = &red[(s * 64 + L) * 48];
#pragma unroll
      for (int g = 0; g < 3; ++g)
#pragma unroll
        for (int mh = 0; mh < 2; ++mh) {
          accI[g][mh] += *(const f32x4*)(p + (g * 2 + mh) * 4);
          accH[g][mh] += *(const f32x4*)(p + 24 + (g * 2 + mh) * 4);
        }
    }
    int j = jt + col;
    float bI[3], bH[3];
#pragma unroll
    for (int g = 0; g < 3; ++g) {
      bI[g] = bih[g * HID + j];
      bH[g] = bhh[g * HID + j];
    }
#pragma unroll
    for (int mh = 0; mh < 2; ++mh) {
#pragma unroll
      for (int r = 0; r < 4; ++r) {
        int b = mh * 16 + quad * 4 + r;  // C/D map: row -> batch, col -> feature j
        float ir = accI[0][mh][r] + bI[0];
        float iz = accI[1][mh][r] + bI[1];
        float in_ = accI[2][mh][r] + bI[2];
        float hr = accH[0][mh][r] + bH[0];
        float hz = accH[1][mh][r] + bH[1];
        float hn = accH[2][mh][r] + bH[2];
        float rr = 1.0f / (1.0f + expf(-(ir + hr)));
        float zz = 1.0f / (1.0f + expf(-(iz + hz)));
        float nn = tanhf(in_ + rr * hn);
        float hold = h_in[b * HID + j];
        float hnew = (1.0f - zz) * nn + zz * hold;
        h_out[b * HID + j] = hnew;
        split_store<NP>(hnew, hb_out, NACT, b * HID + j);
      }
    }
  }
}

// ---------------- FC head: out = h2 @ fc_w^T + fc_b (fp32, straight to d_out slice) ----------------
template <int NP>
__global__ __launch_bounds__(256) void fc_kernel(
    const __hip_bfloat16* __restrict__ fcwp, const float* __restrict__ fcb,
    const __hip_bfloat16* __restrict__ hin,  // planes, stride NACT
    float* __restrict__ outf) {
  __shared__ float red[3 * 64 * 8];
  int tid = threadIdx.x;
  int L = tid & 63, w = tid >> 6;
  int jt = blockIdx.x * 16;
  int col = L & 15, quad = L >> 4;
  int kb = w * 256, aoff = quad * 8;

  f32x4 zero = {0.f, 0.f, 0.f, 0.f};
  f32x4 acc[2] = {zero, zero};
  int row = jt + col;
  int rowc = row < 2500 ? row : 2499;
  for (int it = 0; it < 8; ++it) {
    int k0 = kb + it * 32 + aoff;
    bf16x8 a0[NP], a1[NP], bb[NP];
#pragma unroll
    for (int p = 0; p < NP; ++p) {
      a0[p] = *(const bf16x8*)(hin + p * NACT + col * HID + k0);
      a1[p] = *(const bf16x8*)(hin + p * NACT + (16 + col) * HID + k0);
      bb[p] = *(const bf16x8*)(fcwp + p * NFC + rowc * HID + k0);
    }
#pragma unroll
    for (int p = 0; p < NP; ++p)
#pragma unroll
      for (int q = 0; q < NP - p; ++q) {
        acc[0] = mfma16(a0[p], bb[q], acc[0]);
        acc[1] = mfma16(a1[p], bb[q], acc[1]);
      }
  }
  if (w > 0) {
    float* p = &red[((w - 1) * 64 + L) * 8];
    *(f32x4*)p = acc[0];
    *(f32x4*)(p + 4) = acc[1];
  }
  __syncthreads();
  if (w == 0) {
#pragma unroll
    for (int s = 0; s < 3; ++s) {
      const float* p = &red[(s * 64 + L) * 8];
      acc[0] += *(const f32x4*)p;
      acc[1] += *(const f32x4*)(p + 4);
    }
    int j = jt + col;
    if (j < 2500) {
      float bias = fcb[j];
#pragma unroll
      for (int mh = 0; mh < 2; ++mh)
#pragma unroll
        for (int r = 0; r < 4; ++r) {
          int b = mh * 16 + quad * 4 + r;
          outf[b * 2500 + j] = acc[mh][r] + bias;
        }
    }
  }
}

// ---------------- spectral crop: x_next = C out C^T - S out S^T, split-stored ----------------
template <int NP>
__global__ __launch_bounds__(256) void dft_kernel(
    const float* __restrict__ outf, const float* __restrict__ cosM,
    const float* __restrict__ sinM, __hip_bfloat16* __restrict__ xbp) {
  __shared__ float sq[2500];
  __shared__ float cA[1600], sA[1600], Tm[1600], Um[1600];
  int b = blockIdx.x, tid = threadIdx.x;
  for (int i = tid; i < 2500; i += 256) sq[i] = outf[b * 2500 + i];
  for (int i = tid; i < 1600; i += 256) { cA[i] = cosM[i]; sA[i] = sinM[i]; }
  __syncthreads();
  for (int idx = tid; idx < 1600; idx += 256) {
    int a = idx / 50, n2 = idx % 50;
    float ta = 0.f, ua = 0.f;
    for (int n1 = 0; n1 < 50; ++n1) {
      float v = sq[n1 * 50 + n2];
      ta += v * cA[a * 50 + n1];
      ua += v * sA[a * 50 + n1];
    }
    Tm[idx] = ta;
    Um[idx] = ua;
  }
  __syncthreads();
  for (int idx = tid; idx < 1024; idx += 256) {
    int a = idx >> 5, c = idx & 31;
    float acc = 0.f;
    for (int n2 = 0; n2 < 50; ++n2)
      acc += Tm[a * 50 + n2] * cA[c * 50 + n2] - Um[a * 50 + n2] * sA[c * 50 + n2];
    split_store<NP>(acc, xbp, NACT, b * HID + idx);
  }
}

template <int NP>
static void run_all(const float* x_in, const float* W_ih, const float* W_hh,
                    const float* b_ih, const float* b_hh, const float* fc_w,
                    const float* fc_b, float* dout, char* ws, hipStream_t stream) {
  __hip_bfloat16* WIHP = (__hip_bfloat16*)ws;
  __hip_bfloat16* WHHP = WIHP + (size_t)NP * NWIH;
  __hip_bfloat16* FCWP = WHHP + (size_t)NP * NWIH;
  float* H = (float*)(FCWP + (size_t)NP * NFC);            // [2][3][NACT] fp32
  __hip_bfloat16* HBP = (__hip_bfloat16*)(H + 2 * 3 * NACT); // [2][3][NP][NACT]
  __hip_bfloat16* XBP = HBP + (size_t)2 * 3 * NP * NACT;   // [NP][NACT]
  float* COSM = (float*)(XBP + (size_t)NP * NACT);
  float* SINM = COSM + 1600;

  convert_weights<NP><<<2048, 256, 0, stream>>>(W_ih, W_hh, fc_w, WIHP, WHHP, FCWP);
  setup_kernel<NP><<<512, 256, 0, stream>>>(x_in, H, HBP, XBP, COSM, SINM);

  const int T = 64;
  for (int t = 0; t < T; ++t) {
    int pi = t & 1, po = pi ^ 1;
    for (int l = 0; l < 3; ++l) {
      const __hip_bfloat16* Ain = (l == 0) ? XBP : (HBP + (size_t)((po * 3 + (l - 1)) * NP) * NACT);
      gru_layer<NP><<<64, 256, 0, stream>>>(
          WIHP + (size_t)l * LSTRIDE, WHHP + (size_t)l * LSTRIDE,
          b_ih + l * 3 * HID, b_hh + l * 3 * HID, Ain,
          H + (size_t)(pi * 3 + l) * NACT, HBP + (size_t)((pi * 3 + l) * NP) * NACT,
          H + (size_t)(po * 3 + l) * NACT, HBP + (size_t)((po * 3 + l) * NP) * NACT);
    }
    fc_kernel<NP><<<157, 256, 0, stream>>>(FCWP, fc_b,
                                           HBP + (size_t)((po * 3 + 2) * NP) * NACT,
                                           dout + (size_t)t * BATCH * 2500);
    dft_kernel<NP><<<32, 256, 0, stream>>>(dout + (size_t)t * BATCH * 2500, COSM, SINM, XBP);
  }
}

extern "C" void kernel_launch(void* const* d_in, const int* in_sizes, int n_in,
                              void* d_out, int out_size, void* d_ws, size_t ws_size,
                              hipStream_t stream) {
  const float* x_in = (const float*)d_in[0];
  const float* W_ih = (const float*)d_in[1];
  const float* W_hh = (const float*)d_in[2];
  const float* b_ih = (const float*)d_in[3];
  const float* b_hh = (const float*)d_in[4];
  const float* fc_w = (const float*)d_in[5];
  const float* fc_b = (const float*)d_in[6];
  float* dout = (float*)d_out;
  char* ws = (char*)d_ws;

  auto need = [](int np) -> size_t {
    return (size_t)np * ((size_t)NWIH * 2 + NFC) * 2  // weight planes (bf16)
           + (size_t)2 * 3 * NACT * 4                 // H fp32
           + (size_t)2 * 3 * np * NACT * 2            // HB planes
           + (size_t)np * NACT * 2                    // XB planes
           + 2 * 1600 * 4 + 256;                      // trig + slack
  };
  // NP = planes of bf16 split (3 = exact fp32 emulation). Degrade if ws too small.
  if (ws_size >= need(3))
    run_all<3>(x_in, W_ih, W_hh, b_ih, b_hh, fc_w, fc_b, dout, ws, stream);
  else if (ws_size >= need(2))
    run_all<2>(x_in, W_ih, W_hh, b_ih, b_hh, fc_w, fc_b, dout, ws, stream);
  else
    run_all<1>(x_in, W_ih, W_hh, b_ih, b_hh, fc_w, fc_b, dout, ws, stream);
}